// Round 2
// baseline (543.051 us; speedup 1.0000x reference)
//
#include <hip/hip_runtime.h>
#include <cstdint>

// SREChead: stem 1x1 (128->64) + 2x 3x3 (64->64), each BN+SiLU, then 1x1
// reg(4)/obj(1) heads + YOLOX decode. B=64, 80x80, stride 32.
// R1: bf16 MFMA implicit GEMM, halo-padded NHWC bf16 intermediates (82x82x64)
// so conv loads are unconditional; K-loop fully unrolled; A=weights/B=pixels
// so C/D gives 4 contiguous co per lane -> ushort4 stores.

typedef short short8 __attribute__((ext_vector_type(8)));
typedef float floatx4 __attribute__((ext_vector_type(4)));
typedef float fx4 __attribute__((ext_vector_type(4)));
typedef unsigned short us4 __attribute__((ext_vector_type(4)));

#define NPIX 6400
#define PADIMG (82 * 82 * 64)   // ushorts per padded image

static __device__ __forceinline__ unsigned short f2bf(float f) {
    unsigned u = __builtin_bit_cast(unsigned, f);
    u += 0x7fffu + ((u >> 16) & 1u);      // round-to-nearest-even
    return (unsigned short)(u >> 16);
}

static __device__ __forceinline__ float silu_(float v) {
    return v / (1.0f + __expf(-v));
}

// ---------------------------------------------------------------------------
// Rearrange 3x3 weights [64co][64ci][3][3] fp32 -> bf16 MFMA A-frag order:
// wB[kb(18)][ct(4)][lane(64)][j(8)], co = ct*16+(lane&15),
// k = kb*32+(lane>>4)*8+j, ci = k&63, tap = k>>6 (= dy*3+dx).
__global__ __launch_bounds__(256) void rearr_w_kernel(
    const float* __restrict__ w1, const float* __restrict__ w2,
    unsigned short* __restrict__ wB1, unsigned short* __restrict__ wB2) {
    int idx = blockIdx.x * 256 + threadIdx.x;          // 0..73727
    const float* src = (idx < 36864) ? w1 : w2;
    unsigned short* dst = (idx < 36864) ? wB1 : wB2;
    int e = (idx < 36864) ? idx : idx - 36864;
    int j = e & 7;
    int lane = (e >> 3) & 63;
    int ct = (e >> 9) & 3;
    int kb = e >> 11;
    int co = ct * 16 + (lane & 15);
    int k = kb * 32 + ((lane >> 4) * 8) + j;
    int ci = k & 63;
    int tap = k >> 6;
    dst[e] = f2bf(src[(co * 64 + ci) * 9 + tap]);
}

// ---------------------------------------------------------------------------
// Zero the 1-pixel halo border of both padded feature buffers (re-poisoned
// to 0xAA before every timed launch, so this must run every call).
// 324 border pixels/image * 64 ch / 4-per-thread = 5184 chunks per (buf,b).
__global__ __launch_bounds__(256) void border_kernel(
    unsigned short* __restrict__ f1p, unsigned short* __restrict__ f2p) {
    int t = blockIdx.x * 256 + threadIdx.x;            // 0..663551
    int chunk = t % 5184;
    int bb = t / 5184;                                 // 0..127
    int buf = bb >> 6, b = bb & 63;
    int pix = chunk >> 4;                              // 0..323
    int c4 = (chunk & 15) * 4;
    int row, col;
    if (pix < 82)       { row = 0;  col = pix; }
    else if (pix < 164) { row = 81; col = pix - 82; }
    else { int j = pix - 164; row = 1 + (j >> 1); col = (j & 1) * 81; }
    unsigned short* base = (buf ? f2p : f1p) + (size_t)b * PADIMG + (row * 82 + col) * 64 + c4;
    us4 z = {0, 0, 0, 0};
    *(us4*)base = z;
}

// ---------------------------------------------------------------------------
// Stem: f1p[b][y+1][x+1][co] = silu(bn(sum_ci x[b][ci][p] * W[co][ci]))
// GEMM A=W (m=co), B=x (n=pixel), K=128ci. Wave: 64 co x 64 pix.
__global__ __launch_bounds__(256) void stem_kernel(
    const float* __restrict__ x, const float* __restrict__ w,
    const float* __restrict__ scale, const float* __restrict__ shift,
    unsigned short* __restrict__ f1p) {
    int b = blockIdx.y;
    int wv = threadIdx.x >> 6;
    int lane = threadIdx.x & 63;
    int l15 = lane & 15, q = lane >> 4;
    int pbase = blockIdx.x * 256 + wv * 64;

    // A-frags: weights, register resident. A[m=co][k=ci]
    short8 wf[4][4];     // [ct][kb]
    #pragma unroll
    for (int ct = 0; ct < 4; ++ct) {
        int co = ct * 16 + l15;
        #pragma unroll
        for (int kb = 0; kb < 4; ++kb) {
            const float* wp = w + co * 128 + kb * 32 + q * 8;
            fx4 a = *(const fx4*)wp;
            fx4 bv = *(const fx4*)(wp + 4);
            short8 f;
            #pragma unroll
            for (int j = 0; j < 4; ++j) f[j] = (short)f2bf(a[j]);
            #pragma unroll
            for (int j = 0; j < 4; ++j) f[j + 4] = (short)f2bf(bv[j]);
            wf[ct][kb] = f;
        }
    }
    // BN params, per (ct, r): co = ct*16 + q*4 + r
    float sc[4][4], sh[4][4];
    #pragma unroll
    for (int ct = 0; ct < 4; ++ct)
        #pragma unroll
        for (int r = 0; r < 4; ++r) {
            sc[ct][r] = scale[ct * 16 + q * 4 + r];
            sh[ct][r] = shift[ct * 16 + q * 4 + r];
        }

    floatx4 acc[4][4];   // [ct][pt]
    floatx4 zf = {0.0f, 0.0f, 0.0f, 0.0f};
    #pragma unroll
    for (int ct = 0; ct < 4; ++ct)
        #pragma unroll
        for (int pt = 0; pt < 4; ++pt) acc[ct][pt] = zf;

    #pragma unroll
    for (int kb = 0; kb < 4; ++kb) {
        short8 xf[4];    // B[k=ci][n=pixel]
        #pragma unroll
        for (int pt = 0; pt < 4; ++pt) {
            int p = pbase + pt * 16 + l15;
            const float* xp = x + (size_t)(b * 128 + kb * 32 + q * 8) * NPIX + p;
            short8 f;
            #pragma unroll
            for (int j = 0; j < 8; ++j) f[j] = (short)f2bf(xp[j * NPIX]);
            xf[pt] = f;
        }
        #pragma unroll
        for (int ct = 0; ct < 4; ++ct)
            #pragma unroll
            for (int pt = 0; pt < 4; ++pt)
                acc[ct][pt] = __builtin_amdgcn_mfma_f32_16x16x32_bf16(
                    wf[ct][kb], xf[pt], acc[ct][pt], 0, 0, 0);
    }

    // epilogue: lane holds co = ct*16+q*4+r (contiguous 4), pix = pt*16+l15
    #pragma unroll
    for (int pt = 0; pt < 4; ++pt) {
        int p = pbase + pt * 16 + l15;
        int y = p / 80, xc = p % 80;
        unsigned short* dst = f1p + (size_t)b * PADIMG + ((y + 1) * 82 + (xc + 1)) * 64;
        #pragma unroll
        for (int ct = 0; ct < 4; ++ct) {
            us4 v;
            #pragma unroll
            for (int r = 0; r < 4; ++r)
                v[r] = f2bf(silu_(acc[ct][pt][r] * sc[ct][r] + sh[ct][r]));
            *(us4*)(dst + ct * 16 + q * 4) = v;
        }
    }
}

// ---------------------------------------------------------------------------
// 3x3 conv 64->64 on padded NHWC (no predication), fully unrolled K.
// A=weights (m=co), B=pixels (n=pix). BN+SiLU -> padded NHWC bf16.
__global__ __launch_bounds__(256, 3) void conv3_kernel(
    const unsigned short* __restrict__ fin, const unsigned short* __restrict__ wB,
    const float* __restrict__ scale, const float* __restrict__ shift,
    unsigned short* __restrict__ fout) {
    int b = blockIdx.y;
    int wv = threadIdx.x >> 6;
    int lane = threadIdx.x & 63;
    int l15 = lane & 15, q = lane >> 4;
    int pbase = blockIdx.x * 256 + wv * 64;

    int py[4], px0[4];
    #pragma unroll
    for (int pt = 0; pt < 4; ++pt) {
        int pt16 = pbase + pt * 16;        // 80%16==0 -> tile within one row
        py[pt] = pt16 / 80;
        px0[pt] = pt16 % 80;
    }

    floatx4 acc[4][4];   // [ct][pt]
    floatx4 zf = {0.0f, 0.0f, 0.0f, 0.0f};
    #pragma unroll
    for (int ct = 0; ct < 4; ++ct)
        #pragma unroll
        for (int pt = 0; pt < 4; ++pt) acc[ct][pt] = zf;

    const unsigned short* fb = fin + (size_t)b * PADIMG;

    #pragma unroll
    for (int tap = 0; tap < 9; ++tap) {
        const int dy = tap / 3 - 1, dx = tap % 3 - 1;
        #pragma unroll
        for (int half = 0; half < 2; ++half) {
            const int kb = tap * 2 + half;
            short8 pf[4];
            #pragma unroll
            for (int pt = 0; pt < 4; ++pt) {
                int addr = ((py[pt] + 1 + dy) * 82 + px0[pt] + l15 + 1 + dx) * 64
                         + half * 32 + q * 8;
                pf[pt] = *(const short8*)(fb + addr);
            }
            short8 wf[4];
            #pragma unroll
            for (int ct = 0; ct < 4; ++ct)
                wf[ct] = *(const short8*)(wB + ((kb * 4 + ct) * 64 + lane) * 8);
            #pragma unroll
            for (int ct = 0; ct < 4; ++ct)
                #pragma unroll
                for (int pt = 0; pt < 4; ++pt)
                    acc[ct][pt] = __builtin_amdgcn_mfma_f32_16x16x32_bf16(
                        wf[ct], pf[pt], acc[ct][pt], 0, 0, 0);
        }
    }

    float sc[4][4], sh[4][4];
    #pragma unroll
    for (int ct = 0; ct < 4; ++ct)
        #pragma unroll
        for (int r = 0; r < 4; ++r) {
            sc[ct][r] = scale[ct * 16 + q * 4 + r];
            sh[ct][r] = shift[ct * 16 + q * 4 + r];
        }
    #pragma unroll
    for (int pt = 0; pt < 4; ++pt) {
        unsigned short* dst = fout + (size_t)b * PADIMG
                            + ((py[pt] + 1) * 82 + px0[pt] + l15 + 1) * 64;
        #pragma unroll
        for (int ct = 0; ct < 4; ++ct) {
            us4 v;
            #pragma unroll
            for (int r = 0; r < 4; ++r)
                v[r] = f2bf(silu_(acc[ct][pt][r] * sc[ct][r] + sh[ct][r]));
            *(us4*)(dst + ct * 16 + q * 4) = v;
        }
    }
}

// ---------------------------------------------------------------------------
// c2 conv + BN/SiLU + 1x1 heads (reg 4ch, obj 1ch) + YOLOX decode -> out fp32
__global__ __launch_bounds__(256, 3) void conv_head_kernel(
    const unsigned short* __restrict__ fin, const unsigned short* __restrict__ wB,
    const float* __restrict__ scale, const float* __restrict__ shift,
    const float* __restrict__ reg_w, const float* __restrict__ reg_b,
    const float* __restrict__ obj_w, const float* __restrict__ obj_b,
    float* __restrict__ out) {
    __shared__ unsigned short h_lds[4][64 * 72];   // per-wave 64pix x 64co, pad->72
    int b = blockIdx.y;
    int wv = threadIdx.x >> 6;
    int lane = threadIdx.x & 63;
    int l15 = lane & 15, q = lane >> 4;
    int pbase = blockIdx.x * 256 + wv * 64;

    int py[4], px0[4];
    #pragma unroll
    for (int pt = 0; pt < 4; ++pt) {
        int pt16 = pbase + pt * 16;
        py[pt] = pt16 / 80;
        px0[pt] = pt16 % 80;
    }

    floatx4 acc[4][4];
    floatx4 zf = {0.0f, 0.0f, 0.0f, 0.0f};
    #pragma unroll
    for (int ct = 0; ct < 4; ++ct)
        #pragma unroll
        for (int pt = 0; pt < 4; ++pt) acc[ct][pt] = zf;

    const unsigned short* fb = fin + (size_t)b * PADIMG;

    #pragma unroll
    for (int tap = 0; tap < 9; ++tap) {
        const int dy = tap / 3 - 1, dx = tap % 3 - 1;
        #pragma unroll
        for (int half = 0; half < 2; ++half) {
            const int kb = tap * 2 + half;
            short8 pf[4];
            #pragma unroll
            for (int pt = 0; pt < 4; ++pt) {
                int addr = ((py[pt] + 1 + dy) * 82 + px0[pt] + l15 + 1 + dx) * 64
                         + half * 32 + q * 8;
                pf[pt] = *(const short8*)(fb + addr);
            }
            short8 wf[4];
            #pragma unroll
            for (int ct = 0; ct < 4; ++ct)
                wf[ct] = *(const short8*)(wB + ((kb * 4 + ct) * 64 + lane) * 8);
            #pragma unroll
            for (int ct = 0; ct < 4; ++ct)
                #pragma unroll
                for (int pt = 0; pt < 4; ++pt)
                    acc[ct][pt] = __builtin_amdgcn_mfma_f32_16x16x32_bf16(
                        wf[ct], pf[pt], acc[ct][pt], 0, 0, 0);
        }
    }

    // BN + SiLU -> wave-private LDS tile h[p_loc][co], stride 72
    float sc[4][4], sh[4][4];
    #pragma unroll
    for (int ct = 0; ct < 4; ++ct)
        #pragma unroll
        for (int r = 0; r < 4; ++r) {
            sc[ct][r] = scale[ct * 16 + q * 4 + r];
            sh[ct][r] = shift[ct * 16 + q * 4 + r];
        }
    unsigned short* hp = h_lds[wv];
    #pragma unroll
    for (int pt = 0; pt < 4; ++pt) {
        #pragma unroll
        for (int ct = 0; ct < 4; ++ct) {
            us4 v;
            #pragma unroll
            for (int r = 0; r < 4; ++r)
                v[r] = f2bf(silu_(acc[ct][pt][r] * sc[ct][r] + sh[ct][r]));
            *(us4*)(hp + (pt * 16 + l15) * 72 + ct * 16 + q * 4) = v;
        }
    }
    __syncthreads();

    // head B-frags: B[k=co][n] = reg_w[n][co] (n<4), obj_w[co] (n==4), else 0
    short8 hbf[2];
    #pragma unroll
    for (int kb2 = 0; kb2 < 2; ++kb2) {
        int k0 = kb2 * 32 + q * 8;
        short8 f = {};
        if (l15 < 4) {
            #pragma unroll
            for (int j = 0; j < 8; ++j) f[j] = (short)f2bf(reg_w[l15 * 64 + k0 + j]);
        } else if (l15 == 4) {
            #pragma unroll
            for (int j = 0; j < 8; ++j) f[j] = (short)f2bf(obj_w[k0 + j]);
        }
        hbf[kb2] = f;
    }

    floatx4 acc5[4];
    #pragma unroll
    for (int mt = 0; mt < 4; ++mt) acc5[mt] = zf;
    #pragma unroll
    for (int mt = 0; mt < 4; ++mt)
        #pragma unroll
        for (int kb2 = 0; kb2 < 2; ++kb2) {
            short8 a = *(const short8*)(hp + (mt * 16 + l15) * 72 + kb2 * 32 + q * 8);
            acc5[mt] = __builtin_amdgcn_mfma_f32_16x16x32_bf16(a, hbf[kb2], acc5[mt], 0, 0, 0);
        }

    float bias = 0.0f;
    if (l15 < 4) bias = reg_b[l15];
    else if (l15 == 4) bias = obj_b[0];

    #pragma unroll
    for (int mt = 0; mt < 4; ++mt) {
        #pragma unroll
        for (int r = 0; r < 4; ++r) {
            int p = pbase + mt * 16 + q * 4 + r;
            if (l15 < 5) {
                float v = acc5[mt][r] + bias;
                float gx = (float)(px0[mt] + q * 4 + r);
                float gy = (float)py[mt];
                float o;
                if (l15 == 0)      o = (v + gx) * 32.0f;
                else if (l15 == 1) o = (v + gy) * 32.0f;
                else if (l15 < 4)  o = __expf(v) * 32.0f;
                else               o = 1.0f / (1.0f + __expf(-v));
                out[(size_t)(b * NPIX + p) * 5 + l15] = o;
            }
        }
    }
}

// ---------------------------------------------------------------------------
extern "C" void kernel_launch(void* const* d_in, const int* in_sizes, int n_in,
                              void* d_out, int out_size, void* d_ws, size_t ws_size,
                              hipStream_t stream) {
    const float* x          = (const float*)d_in[0];
    const float* stem_w     = (const float*)d_in[1];
    const float* stem_scale = (const float*)d_in[2];
    const float* stem_shift = (const float*)d_in[3];
    const float* c1_w       = (const float*)d_in[4];
    const float* c1_scale   = (const float*)d_in[5];
    const float* c1_shift   = (const float*)d_in[6];
    const float* c2_w       = (const float*)d_in[7];
    const float* c2_scale   = (const float*)d_in[8];
    const float* c2_shift   = (const float*)d_in[9];
    const float* reg_w      = (const float*)d_in[10];
    const float* reg_b      = (const float*)d_in[11];
    const float* obj_w      = (const float*)d_in[12];
    const float* obj_b      = (const float*)d_in[13];
    float* out = (float*)d_out;

    // ws layout (ushort units): wB1[36864] | wB2[36864] | f1p[64*PADIMG] | f2p[same]
    const size_t needed = ((size_t)73728 + 2 * (size_t)64 * PADIMG) * 2;
    if (ws_size < needed) return;  // guard: avoid OOB writes if ws too small

    unsigned short* ws  = (unsigned short*)d_ws;
    unsigned short* wB1 = ws;
    unsigned short* wB2 = ws + 36864;
    unsigned short* f1p = ws + 73728;
    unsigned short* f2p = f1p + (size_t)64 * PADIMG;

    rearr_w_kernel<<<288, 256, 0, stream>>>(c1_w, c2_w, wB1, wB2);
    border_kernel<<<2592, 256, 0, stream>>>(f1p, f2p);
    stem_kernel<<<dim3(25, 64), 256, 0, stream>>>(x, stem_w, stem_scale, stem_shift, f1p);
    conv3_kernel<<<dim3(25, 64), 256, 0, stream>>>(f1p, wB1, c1_scale, c1_shift, f2p);
    conv_head_kernel<<<dim3(25, 64), 256, 0, stream>>>(f2p, wB2, c2_scale, c2_shift,
                                                       reg_w, reg_b, obj_w, obj_b, out);
}